// Round 12
// baseline (1054.890 us; speedup 1.0000x reference)
//
#include <hip/hip_runtime.h>
#include <stdint.h>
#include <math.h>

#define TTOK 8192
#define DDIM 1024
#define FDIM 4096
#define NEXP 8
#define NASG (TTOK*2)
#define MT128 64   // max 128-row tiles per expert

#define RTRB (TTOK/4)                              // 2048 router blocks
#define TR1B (NEXP*(DDIM/64)*(FDIM/64))            // 8192 w1 tiles
#define TR2B (NEXP*(FDIM/64)*(DDIM/64))            // 8192 w2 tiles

typedef __attribute__((ext_vector_type(8))) short bf16x8;
typedef __attribute__((ext_vector_type(4))) float f32x4;
typedef __attribute__((ext_vector_type(4))) float f4v;
typedef __attribute__((ext_vector_type(8))) unsigned short u16x8;

__device__ __forceinline__ unsigned short f2bf(float f) {
  union { float f; unsigned int u; } v; v.f = f;
  unsigned int u = v.u;
  u += 0x7fffu + ((u >> 16) & 1u);   // round-to-nearest-even
  return (unsigned short)(u >> 16);
}

__device__ __forceinline__ void gload16(const void* g, void* l) {
  __builtin_amdgcn_global_load_lds(
    (__attribute__((address_space(1))) unsigned int*)(uintptr_t)g,
    (__attribute__((address_space(3))) unsigned int*)(uintptr_t)l,
    16, 0, 0);
}

// ===== prep: router (blocks 0..RTRB) + weight transpose (rest), co-scheduled =====
// router: one wave per token, fp64 accumulate, emits xb bf16 + topk + counts
// transpose: [E][R][C] f32 -> [E][C][R] bf16 for w1 and w2
__global__ __launch_bounds__(256) void prep_kernel(
    const float* __restrict__ x, const float* __restrict__ rw,
    const float* __restrict__ rb, int* __restrict__ topi,
    float* __restrict__ topw, int* __restrict__ counts,
    unsigned short* __restrict__ xb,
    const float* __restrict__ w1, unsigned short* __restrict__ w1t,
    const float* __restrict__ w2, unsigned short* __restrict__ w2t)
{
  __shared__ float tile[64][65];
  int blk = blockIdx.x;
  if (blk < RTRB) {
    int wave = threadIdx.x >> 6;
    int lane = threadIdx.x & 63;
    int t = blk * 4 + wave;
    if (t >= TTOK) return;
    double acc[8];
#pragma unroll
    for (int e = 0; e < 8; e++) acc[e] = 0.0;
    const float* xr = x + (size_t)t * DDIM;
    unsigned short* xbr = xb + (size_t)t * DDIM;
    for (int d = lane; d < DDIM; d += 64) {
      float xf = xr[d];
      xbr[d] = f2bf(xf);
      double xv = (double)xf;
      const float* rwr = rw + (size_t)d * 8;
#pragma unroll
      for (int e = 0; e < 8; e++) acc[e] += xv * (double)rwr[e];
    }
#pragma unroll
    for (int e = 0; e < 8; e++) {
      for (int off = 32; off >= 1; off >>= 1)
        acc[e] += __shfl_xor(acc[e], off);
    }
    if (lane == 0) {
      float lg[8];
#pragma unroll
      for (int e = 0; e < 8; e++) lg[e] = (float)acc[e] + rb[e];
      int i0 = 0;
      for (int e = 1; e < 8; e++) if (lg[e] > lg[i0]) i0 = e;   // ties -> lowest idx
      int i1 = -1;
      for (int e = 0; e < 8; e++) {
        if (e == i0) continue;
        if (i1 < 0 || lg[e] > lg[i1]) i1 = e;
      }
      double z = exp((double)lg[i1] - (double)lg[i0]);
      float w0 = (float)(1.0 / (1.0 + z));
      topi[t*2]   = i0;  topi[t*2+1] = i1;
      topw[t*2]   = w0;  topw[t*2+1] = 1.0f - w0;
      atomicAdd(&counts[i0], 1);
      atomicAdd(&counts[i1], 1);
    }
    return;
  }
  // ---- transpose part ----
  int b = blk - RTRB;
  const float* w; unsigned short* wt; int R, C;
  if (b < TR1B) { w = w1; wt = w1t; R = DDIM; C = FDIM; }
  else { b -= TR1B; w = w2; wt = w2t; R = FDIM; C = DDIM; }
  int tilesPerRow = C >> 6;
  int tilesPerMat = (R >> 6) * tilesPerRow;
  int e = b / tilesPerMat;
  int rem = b - e * tilesPerMat;
  int tr = rem / tilesPerRow;
  int tc = rem - tr * tilesPerRow;
  int tid = threadIdx.x;
  size_t ibase = (size_t)e*R*C + ((size_t)tr*64)*C + (size_t)tc*64;
#pragma unroll
  for (int i = 0; i < 16; i++) {
    int idx = tid + i*256;
    int r = idx >> 6, c = idx & 63;
    tile[r][c] = w[ibase + (size_t)r*C + c];
  }
  __syncthreads();
  size_t obase = (size_t)e*R*C + ((size_t)tc*64)*R + (size_t)tr*64;
#pragma unroll
  for (int i = 0; i < 16; i++) {
    int idx = tid + i*256;
    int r = idx >> 6, c = idx & 63;
    wt[obase + (size_t)r*R + c] = f2bf(tile[c][r]);
  }
}

// ------ deterministic stable counting sort (single block; includes scan) ------
__global__ __launch_bounds__(256) void permbuild_kernel(
    const int* __restrict__ topi, const int* __restrict__ counts,
    int* __restrict__ offsets, int* __restrict__ perm, int* __restrict__ islot)
{
  __shared__ int hist[256 * 8];
  __shared__ int offs[NEXP + 1];
  int tid = threadIdx.x;
  if (tid == 0) {
    int s = 0;
    for (int e = 0; e < 8; e++) { offs[e] = s; s += counts[e]; }
    offs[8] = s;
    for (int e = 0; e <= 8; e++) offsets[e] = offs[e];
  }
  int cnt[8];
#pragma unroll
  for (int e = 0; e < 8; e++) cnt[e] = 0;
  int base = tid * 64;
  for (int i = 0; i < 64; i++) cnt[topi[base + i]]++;
#pragma unroll
  for (int e = 0; e < 8; e++) hist[tid*8 + e] = cnt[e];
  __syncthreads();
  if (tid < 8) {
    int s = 0;
    for (int th = 0; th < 256; th++) { int v = hist[th*8 + tid]; hist[th*8 + tid] = s; s += v; }
  }
  __syncthreads();
  int pos[8];
#pragma unroll
  for (int e = 0; e < 8; e++) pos[e] = offs[e] + hist[tid*8 + e];
  for (int i = 0; i < 64; i++) {
    int a = base + i;
    int e = topi[a];
    int p = pos[e]++;
    perm[p] = a >> 1;
    islot[a] = p;
  }
}

// ========= 128x128 grouped GEMM, m97-faithful (multi-block overlap) ==========
// 256 threads (4 waves, 2x2), per-wave 64x64 output. BK=64. LDS 32KB single
// buffer (A 16KB + B 16KB), 2 __syncthreads per K-step; ~3-5 blocks/CU hide
// the drains. Swizzle byte ^= (row&7)<<4: inverse on global src, fwd on reads.

template<int KDIM, int NDIM, bool GELU>
__global__ __launch_bounds__(256, 5) void gemm128(
    const unsigned short* __restrict__ Asrc,
    const unsigned short* __restrict__ Bsrc,
    const float* __restrict__ bias,
    const int* __restrict__ perm,
    const int* __restrict__ offsets,
    void* __restrict__ Cout)
{
  constexpr int KT = KDIM / 64;
  constexpr int NT = NDIM / 128;
  int b = blockIdx.x;
  int e = b / (MT128 * NT);
  int rem = b - e * (MT128 * NT);
  int rt = rem / NT;
  int nt = rem - rt * NT;
  int off = offsets[e];
  int n_e = offsets[e+1] - off;
  if (rt * 128 >= n_e) return;

  __shared__ __align__(16) unsigned short lds[2 * 128 * 64];   // 32 KiB
  char* ldsA = (char*)lds;            // A: 128 rows x 128B
  char* ldsB = (char*)lds + 16384;    // B: 128 rows x 128B

  int tid = threadIdx.x;
  int lane = tid & 63;
  int wid = tid >> 6;          // 0..3
  int wr = wid >> 1;           // 0..1 (M strip)
  int wc = wid & 1;            // 0..1 (N strip)
  int tb0 = (lane >> 4) * 16;
  int rA = wr*64 + (lane & 15);
  int rB = wc*64 + (lane & 15);
  int xa  = (rA & 7) << 4;
  int xbw = (rB & 7) << 4;
  int aks0 = rA*128 + ( tb0       ^ xa);
  int aks1 = rA*128 + ((64 + tb0) ^ xa);
  int bks0 = rB*128 + ( tb0       ^ xbw);
  int bks1 = rB*128 + ((64 + tb0) ^ xbw);

  // staging: 4 A-slots + 4 B-slots per thread (1024 slots = 128 rows x 8 chunks)
  const char* srcA[4];
  const char* srcB[4];
#pragma unroll
  for (int i = 0; i < 4; i++) {
    int slot = tid + i*256;
    int r = slot >> 3;
    int kc = (slot & 7) ^ (r & 7);   // inverse swizzle on global k-chunk
    int g = off + rt*128 + r;
    if (g > NASG-1) g = NASG-1;
    size_t ar = GELU ? (size_t)perm[g] : (size_t)g;
    srcA[i] = (const char*)Asrc + (ar * KDIM + (size_t)kc*8) * 2;
    int col = nt*128 + r;
    srcB[i] = (const char*)Bsrc + (((size_t)e*NDIM + col) * KDIM + (size_t)kc*8) * 2;
  }
  int dstOff = tid * 16;

  f32x4 acc[4][4];
#pragma unroll
  for (int m = 0; m < 4; m++)
#pragma unroll
    for (int n = 0; n < 4; n++) acc[m][n] = (f32x4){0.f,0.f,0.f,0.f};

#pragma unroll 1
  for (int kt = 0; kt < KT; ++kt) {
    __syncthreads();   // previous compute done before overwrite
#pragma unroll
    for (int i = 0; i < 4; i++) {
      gload16(srcA[i] + (size_t)kt*128, ldsA + dstOff + i*4096);
      gload16(srcB[i] + (size_t)kt*128, ldsB + dstOff + i*4096);
    }
    __syncthreads();   // compiler-inserted vmcnt(0) drain: tile ready
#pragma unroll
    for (int ks = 0; ks < 2; ks++) {
      int ao = ks ? aks1 : aks0;
      int bo = ks ? bks1 : bks0;
      bf16x8 a[4], bb[4];
#pragma unroll
      for (int mi = 0; mi < 4; mi++) a[mi]  = *(const bf16x8*)(ldsA + mi*2048 + ao);
#pragma unroll
      for (int ni = 0; ni < 4; ni++) bb[ni] = *(const bf16x8*)(ldsB + ni*2048 + bo);
#pragma unroll
      for (int mi = 0; mi < 4; mi++)
#pragma unroll
        for (int ni = 0; ni < 4; ni++)
          acc[mi][ni] = __builtin_amdgcn_mfma_f32_16x16x32_bf16(a[mi], bb[ni], acc[mi][ni], 0, 0, 0);
    }
  }

  // epilogue
  int rq = (lane >> 4) * 4;
  int lc = lane & 15;
  if (GELU) {
    unsigned short* H = (unsigned short*)Cout;
#pragma unroll
    for (int mi = 0; mi < 4; mi++)
#pragma unroll
      for (int j = 0; j < 4; j++) {
        int sl = rt*128 + wr*64 + mi*16 + rq + j;
        if (sl < n_e) {
          size_t hrow = (size_t)(off + sl) * NDIM;
#pragma unroll
          for (int ni = 0; ni < 4; ni++) {
            int col = nt*128 + wc*64 + ni*16 + lc;
            float v = acc[mi][ni][j] + bias[e*NDIM + col];
            float g = 0.5f * v * (1.0f + erff(v * 0.70710678118654752f));
            H[hrow + col] = f2bf(g);
          }
        }
      }
  } else {
    float* Y = (float*)Cout;
#pragma unroll
    for (int mi = 0; mi < 4; mi++)
#pragma unroll
      for (int j = 0; j < 4; j++) {
        int sl = rt*128 + wr*64 + mi*16 + rq + j;
        if (sl < n_e) {
          size_t yrow = (size_t)(off + sl) * NDIM;
#pragma unroll
          for (int ni = 0; ni < 4; ni++) {
            int col = nt*128 + wc*64 + ni*16 + lc;
            Y[yrow + col] = acc[mi][ni][j];
          }
        }
      }
  }
}

// ---------- combine: out[t] = sum_k w_k * (Y[slot_k] + b2[e_k]) ----------
__global__ __launch_bounds__(256) void combine_kernel(
    const float* __restrict__ Y, const float* __restrict__ b2,
    const int* __restrict__ topi, const float* __restrict__ topw,
    const int* __restrict__ islot, float* __restrict__ out)
{
  int t = blockIdx.x;
  int s0 = islot[t*2], s1 = islot[t*2+1];
  int e0 = topi[t*2],  e1 = topi[t*2+1];
  float w0 = topw[t*2], w1 = topw[t*2+1];
  int d = threadIdx.x * 4;
  f4v y0 = *(const f4v*)(Y + (size_t)s0*DDIM + d);
  f4v y1 = *(const f4v*)(Y + (size_t)s1*DDIM + d);
  f4v c0 = *(const f4v*)(b2 + (size_t)e0*DDIM + d);
  f4v c1 = *(const f4v*)(b2 + (size_t)e1*DDIM + d);
  f4v o = w0*(y0+c0) + w1*(y1+c1);
  *(f4v*)(out + (size_t)t*DDIM + d) = o;
}

extern "C" void kernel_launch(void* const* d_in, const int* in_sizes, int n_in,
                              void* d_out, int out_size, void* d_ws, size_t ws_size,
                              hipStream_t stream) {
  const float* x  = (const float*)d_in[0];
  const float* w1 = (const float*)d_in[1];
  const float* b1 = (const float*)d_in[2];
  const float* w2 = (const float*)d_in[3];
  const float* b2 = (const float*)d_in[4];
  const float* rw = (const float*)d_in[5];
  const float* rb = (const float*)d_in[6];
  float* out = (float*)d_out;

  char* p = (char*)d_ws;
  size_t o = 0;
  auto take = [&](size_t bytes) -> void* {
    void* r = p + o;
    o = (o + bytes + 255) & ~(size_t)255;
    return r;
  };
  int*            counts  = (int*)take(NEXP * 4);
  int*            offsets = (int*)take((NEXP + 1) * 4);
  int*            topi    = (int*)take((size_t)NASG * 4);
  float*          topw    = (float*)take((size_t)NASG * 4);
  int*            perm    = (int*)take((size_t)NASG * 4);
  int*            islot   = (int*)take((size_t)NASG * 4);
  unsigned short* w1t     = (unsigned short*)take((size_t)NEXP * FDIM * DDIM * 2);
  unsigned short* xb      = (unsigned short*)take((size_t)TTOK * DDIM * 2);
  unsigned short* w2t     = (unsigned short*)take((size_t)NEXP * DDIM * FDIM * 2);
  unsigned short* H       = (unsigned short*)take((size_t)NASG * FDIM * 2);
  // Y aliases w1t (dead after gemm1): NASG*DDIM*4 = 64 MiB = exactly w1t's size
  float*          Y       = (float*)w1t;

  if (o > ws_size) {   // workspace insufficient: fail visibly (zeros)
    hipMemsetAsync(d_out, 0, (size_t)out_size * 4, stream);
    return;
  }

  hipMemsetAsync(counts, 0, NEXP * 4, stream);

  prep_kernel<<<RTRB + TR1B + TR2B, 256, 0, stream>>>(
      x, rw, rb, topi, topw, counts, xb, w1, w1t, w2, w2t);
  permbuild_kernel<<<1, 256, 0, stream>>>(topi, counts, offsets, perm, islot);
  gemm128<DDIM, FDIM, true ><<<NEXP*MT128*(FDIM/128), 256, 0, stream>>>(xb, w1t, b1, perm, offsets, (void*)H);
  gemm128<FDIM, DDIM, false><<<NEXP*MT128*(DDIM/128), 256, 0, stream>>>(H, w2t, nullptr, nullptr, offsets, (void*)Y);
  combine_kernel<<<TTOK, 256, 0, stream>>>(Y, b2, topi, topw, islot, out);
}

// Round 13
// 740.110 us; speedup vs baseline: 1.4253x; 1.4253x over previous
//
#include <hip/hip_runtime.h>
#include <stdint.h>
#include <math.h>

#define TTOK 8192
#define DDIM 1024
#define FDIM 4096
#define NEXP 8
#define NASG (TTOK*2)
#define MT128 64   // max 128-row tiles per expert

#define RTRB (TTOK/4)                              // 2048 router blocks
#define TR1B (NEXP*(DDIM/64)*(FDIM/64))            // 8192 w1 tiles
#define TR2B (NEXP*(FDIM/64)*(DDIM/64))            // 8192 w2 tiles

typedef __attribute__((ext_vector_type(8))) short bf16x8;
typedef __attribute__((ext_vector_type(4))) float f32x4;
typedef __attribute__((ext_vector_type(4))) float f4v;
typedef __attribute__((ext_vector_type(4))) unsigned short u16x4;

__device__ __forceinline__ unsigned short f2bf(float f) {
  union { float f; unsigned int u; } v; v.f = f;
  unsigned int u = v.u;
  u += 0x7fffu + ((u >> 16) & 1u);   // round-to-nearest-even
  return (unsigned short)(u >> 16);
}

__device__ __forceinline__ void gload16(const void* g, void* l) {
  __builtin_amdgcn_global_load_lds(
    (__attribute__((address_space(1))) unsigned int*)(uintptr_t)g,
    (__attribute__((address_space(3))) unsigned int*)(uintptr_t)l,
    16, 0, 0);
}

// ===== prep: router (blocks 0..RTRB) + weight transpose (rest), co-scheduled =====
// router: one wave per token, fp64 accumulate, emits xb bf16 + topk + counts
// transpose: [E][R][C] f32 -> [E][C][R] bf16 for w1 and w2 (ushort4 stores)
__global__ __launch_bounds__(256) void prep_kernel(
    const float* __restrict__ x, const float* __restrict__ rw,
    const float* __restrict__ rb, int* __restrict__ topi,
    float* __restrict__ topw, int* __restrict__ counts,
    unsigned short* __restrict__ xb,
    const float* __restrict__ w1, unsigned short* __restrict__ w1t,
    const float* __restrict__ w2, unsigned short* __restrict__ w2t)
{
  __shared__ float tile[64][65];
  int blk = blockIdx.x;
  if (blk < RTRB) {
    int wave = threadIdx.x >> 6;
    int lane = threadIdx.x & 63;
    int t = blk * 4 + wave;
    if (t >= TTOK) return;
    double acc[8];
#pragma unroll
    for (int e = 0; e < 8; e++) acc[e] = 0.0;
    const float* xr = x + (size_t)t * DDIM;
    unsigned short* xbr = xb + (size_t)t * DDIM;
    for (int d = lane; d < DDIM; d += 64) {
      float xf = xr[d];
      xbr[d] = f2bf(xf);
      double xv = (double)xf;
      const float* rwr = rw + (size_t)d * 8;
#pragma unroll
      for (int e = 0; e < 8; e++) acc[e] += xv * (double)rwr[e];
    }
#pragma unroll
    for (int e = 0; e < 8; e++) {
      for (int off = 32; off >= 1; off >>= 1)
        acc[e] += __shfl_xor(acc[e], off);
    }
    if (lane == 0) {
      float lg[8];
#pragma unroll
      for (int e = 0; e < 8; e++) lg[e] = (float)acc[e] + rb[e];
      int i0 = 0;
      for (int e = 1; e < 8; e++) if (lg[e] > lg[i0]) i0 = e;   // ties -> lowest idx
      int i1 = -1;
      for (int e = 0; e < 8; e++) {
        if (e == i0) continue;
        if (i1 < 0 || lg[e] > lg[i1]) i1 = e;
      }
      double z = exp((double)lg[i1] - (double)lg[i0]);
      float w0 = (float)(1.0 / (1.0 + z));
      topi[t*2]   = i0;  topi[t*2+1] = i1;
      topw[t*2]   = w0;  topw[t*2+1] = 1.0f - w0;
      atomicAdd(&counts[i0], 1);
      atomicAdd(&counts[i1], 1);
    }
    return;
  }
  // ---- transpose part ----
  int b = blk - RTRB;
  const float* w; unsigned short* wt; int R, C;
  if (b < TR1B) { w = w1; wt = w1t; R = DDIM; C = FDIM; }
  else { b -= TR1B; w = w2; wt = w2t; R = FDIM; C = DDIM; }
  int tilesPerRow = C >> 6;
  int tilesPerMat = (R >> 6) * tilesPerRow;
  int e = b / tilesPerMat;
  int rem = b - e * tilesPerMat;
  int tr = rem / tilesPerRow;
  int tc = rem - tr * tilesPerRow;
  int tid = threadIdx.x;
  size_t ibase = (size_t)e*R*C + ((size_t)tr*64)*C + (size_t)tc*64;
#pragma unroll
  for (int i = 0; i < 16; i++) {
    int idx = tid + i*256;
    int r = idx >> 6, c = idx & 63;
    tile[r][c] = w[ibase + (size_t)r*C + c];
  }
  __syncthreads();
  // output [C][R]: out[tc*64 + r][tr*64 + c] = tile[c][r]; 4 cols per lane
  size_t obase = (size_t)e*R*C + ((size_t)tc*64)*R + (size_t)tr*64;
#pragma unroll
  for (int i = 0; i < 4; i++) {
    int idx = tid + i*256;          // 0..1023
    int r  = idx >> 4;              // output row 0..63
    int c4 = (idx & 15) * 4;        // output col group
    u16x4 v;
    v[0] = f2bf(tile[c4+0][r]);
    v[1] = f2bf(tile[c4+1][r]);
    v[2] = f2bf(tile[c4+2][r]);
    v[3] = f2bf(tile[c4+3][r]);
    *(u16x4*)(wt + obase + (size_t)r*R + c4) = v;
  }
}

// ------ deterministic stable counting sort (single block; includes scan) ------
__global__ __launch_bounds__(256) void permbuild_kernel(
    const int* __restrict__ topi, const int* __restrict__ counts,
    int* __restrict__ offsets, int* __restrict__ perm, int* __restrict__ islot)
{
  __shared__ int hist[256 * 8];
  __shared__ int offs[NEXP + 1];
  int tid = threadIdx.x;
  if (tid == 0) {
    int s = 0;
    for (int e = 0; e < 8; e++) { offs[e] = s; s += counts[e]; }
    offs[8] = s;
    for (int e = 0; e <= 8; e++) offsets[e] = offs[e];
  }
  int cnt[8];
#pragma unroll
  for (int e = 0; e < 8; e++) cnt[e] = 0;
  int base = tid * 64;
  for (int i = 0; i < 64; i++) cnt[topi[base + i]]++;
#pragma unroll
  for (int e = 0; e < 8; e++) hist[tid*8 + e] = cnt[e];
  __syncthreads();
  if (tid < 8) {
    int s = 0;
    for (int th = 0; th < 256; th++) { int v = hist[th*8 + tid]; hist[th*8 + tid] = s; s += v; }
  }
  __syncthreads();
  int pos[8];
#pragma unroll
  for (int e = 0; e < 8; e++) pos[e] = offs[e] + hist[tid*8 + e];
  for (int i = 0; i < 64; i++) {
    int a = base + i;
    int e = topi[a];
    int p = pos[e]++;
    perm[p] = a >> 1;
    islot[a] = p;
  }
}

// ========= 128x128 grouped GEMM, m97-faithful (multi-block overlap) ==========
// r10-verbatim: 256 threads (4 waves, 2x2), per-wave 64x64. BK=64. LDS 32KB
// single buffer, 2 __syncthreads per K-step; ~3 blocks/CU hide the drains.
// NO __launch_bounds__ (r12 showed (256,5) -> VGPR 48, L2 thrash, 1.7x slower).
// Swizzle byte ^= (row&7)<<4: inverse on global src, fwd on ds reads.

template<int KDIM, int NDIM, bool GELU>
__global__ void gemm128(
    const unsigned short* __restrict__ Asrc,
    const unsigned short* __restrict__ Bsrc,
    const float* __restrict__ bias,
    const int* __restrict__ perm,
    const int* __restrict__ offsets,
    void* __restrict__ Cout)
{
  constexpr int KT = KDIM / 64;
  constexpr int NT = NDIM / 128;
  int b = blockIdx.x;
  int e = b / (MT128 * NT);
  int rem = b - e * (MT128 * NT);
  int rt = rem / NT;
  int nt = rem - rt * NT;
  int off = offsets[e];
  int n_e = offsets[e+1] - off;
  if (rt * 128 >= n_e) return;

  __shared__ __align__(16) unsigned short lds[2 * 128 * 64];   // 32 KiB
  char* ldsA = (char*)lds;            // A: 128 rows x 128B
  char* ldsB = (char*)lds + 16384;    // B: 128 rows x 128B

  int tid = threadIdx.x;
  int lane = tid & 63;
  int wid = tid >> 6;          // 0..3
  int wr = wid >> 1;           // 0..1 (M strip)
  int wc = wid & 1;            // 0..1 (N strip)
  int tb0 = (lane >> 4) * 16;
  int rA = wr*64 + (lane & 15);
  int rB = wc*64 + (lane & 15);
  int xa  = (rA & 7) << 4;
  int xbw = (rB & 7) << 4;
  int aks0 = rA*128 + ( tb0       ^ xa);
  int aks1 = rA*128 + ((64 + tb0) ^ xa);
  int bks0 = rB*128 + ( tb0       ^ xbw);
  int bks1 = rB*128 + ((64 + tb0) ^ xbw);

  // staging: 4 A-slots + 4 B-slots per thread (1024 slots = 128 rows x 8 chunks)
  const char* srcA[4];
  const char* srcB[4];
#pragma unroll
  for (int i = 0; i < 4; i++) {
    int slot = tid + i*256;
    int r = slot >> 3;
    int kc = (slot & 7) ^ (r & 7);   // inverse swizzle on global k-chunk
    int g = off + rt*128 + r;
    if (g > NASG-1) g = NASG-1;
    size_t ar = GELU ? (size_t)perm[g] : (size_t)g;
    srcA[i] = (const char*)Asrc + (ar * KDIM + (size_t)kc*8) * 2;
    int col = nt*128 + r;
    srcB[i] = (const char*)Bsrc + (((size_t)e*NDIM + col) * KDIM + (size_t)kc*8) * 2;
  }
  int dstOff = tid * 16;

  f32x4 acc[4][4];
#pragma unroll
  for (int m = 0; m < 4; m++)
#pragma unroll
    for (int n = 0; n < 4; n++) acc[m][n] = (f32x4){0.f,0.f,0.f,0.f};

#pragma unroll 1
  for (int kt = 0; kt < KT; ++kt) {
    __syncthreads();   // previous compute done before overwrite
#pragma unroll
    for (int i = 0; i < 4; i++) {
      gload16(srcA[i] + (size_t)kt*128, ldsA + dstOff + i*4096);
      gload16(srcB[i] + (size_t)kt*128, ldsB + dstOff + i*4096);
    }
    __syncthreads();   // compiler-inserted vmcnt(0) drain: tile ready
#pragma unroll
    for (int ks = 0; ks < 2; ks++) {
      int ao = ks ? aks1 : aks0;
      int bo = ks ? bks1 : bks0;
      bf16x8 a[4], bb[4];
#pragma unroll
      for (int mi = 0; mi < 4; mi++) a[mi]  = *(const bf16x8*)(ldsA + mi*2048 + ao);
#pragma unroll
      for (int ni = 0; ni < 4; ni++) bb[ni] = *(const bf16x8*)(ldsB + ni*2048 + bo);
#pragma unroll
      for (int mi = 0; mi < 4; mi++)
#pragma unroll
        for (int ni = 0; ni < 4; ni++)
          acc[mi][ni] = __builtin_amdgcn_mfma_f32_16x16x32_bf16(a[mi], bb[ni], acc[mi][ni], 0, 0, 0);
    }
  }

  // epilogue
  int rq = (lane >> 4) * 4;
  int lc = lane & 15;
  if (GELU) {
    unsigned short* H = (unsigned short*)Cout;
#pragma unroll
    for (int mi = 0; mi < 4; mi++)
#pragma unroll
      for (int j = 0; j < 4; j++) {
        int sl = rt*128 + wr*64 + mi*16 + rq + j;
        if (sl < n_e) {
          size_t hrow = (size_t)(off + sl) * NDIM;
#pragma unroll
          for (int ni = 0; ni < 4; ni++) {
            int col = nt*128 + wc*64 + ni*16 + lc;
            float v = acc[mi][ni][j] + bias[e*NDIM + col];
            float g = 0.5f * v * (1.0f + erff(v * 0.70710678118654752f));
            H[hrow + col] = f2bf(g);
          }
        }
      }
  } else {
    float* Y = (float*)Cout;
#pragma unroll
    for (int mi = 0; mi < 4; mi++)
#pragma unroll
      for (int j = 0; j < 4; j++) {
        int sl = rt*128 + wr*64 + mi*16 + rq + j;
        if (sl < n_e) {
          size_t yrow = (size_t)(off + sl) * NDIM;
#pragma unroll
          for (int ni = 0; ni < 4; ni++) {
            int col = nt*128 + wc*64 + ni*16 + lc;
            Y[yrow + col] = acc[mi][ni][j];
          }
        }
      }
  }
}

// ---------- combine: out[t] = sum_k w_k * (Y[slot_k] + b2[e_k]) ----------
__global__ __launch_bounds__(256) void combine_kernel(
    const float* __restrict__ Y, const float* __restrict__ b2,
    const int* __restrict__ topi, const float* __restrict__ topw,
    const int* __restrict__ islot, float* __restrict__ out)
{
  int t = blockIdx.x;
  int s0 = islot[t*2], s1 = islot[t*2+1];
  int e0 = topi[t*2],  e1 = topi[t*2+1];
  float w0 = topw[t*2], w1 = topw[t*2+1];
  int d = threadIdx.x * 4;
  f4v y0 = *(const f4v*)(Y + (size_t)s0*DDIM + d);
  f4v y1 = *(const f4v*)(Y + (size_t)s1*DDIM + d);
  f4v c0 = *(const f4v*)(b2 + (size_t)e0*DDIM + d);
  f4v c1 = *(const f4v*)(b2 + (size_t)e1*DDIM + d);
  f4v o = w0*(y0+c0) + w1*(y1+c1);
  *(f4v*)(out + (size_t)t*DDIM + d) = o;
}

extern "C" void kernel_launch(void* const* d_in, const int* in_sizes, int n_in,
                              void* d_out, int out_size, void* d_ws, size_t ws_size,
                              hipStream_t stream) {
  const float* x  = (const float*)d_in[0];
  const float* w1 = (const float*)d_in[1];
  const float* b1 = (const float*)d_in[2];
  const float* w2 = (const float*)d_in[3];
  const float* b2 = (const float*)d_in[4];
  const float* rw = (const float*)d_in[5];
  const float* rb = (const float*)d_in[6];
  float* out = (float*)d_out;

  char* p = (char*)d_ws;
  size_t o = 0;
  auto take = [&](size_t bytes) -> void* {
    void* r = p + o;
    o = (o + bytes + 255) & ~(size_t)255;
    return r;
  };
  int*            counts  = (int*)take(NEXP * 4);
  int*            offsets = (int*)take((NEXP + 1) * 4);
  int*            topi    = (int*)take((size_t)NASG * 4);
  float*          topw    = (float*)take((size_t)NASG * 4);
  int*            perm    = (int*)take((size_t)NASG * 4);
  int*            islot   = (int*)take((size_t)NASG * 4);
  unsigned short* w1t     = (unsigned short*)take((size_t)NEXP * FDIM * DDIM * 2);
  unsigned short* xb      = (unsigned short*)take((size_t)TTOK * DDIM * 2);
  unsigned short* w2t     = (unsigned short*)take((size_t)NEXP * DDIM * FDIM * 2);
  unsigned short* H       = (unsigned short*)take((size_t)NASG * FDIM * 2);
  // Y aliases w1t (dead after gemm1): NASG*DDIM*4 = 64 MiB = exactly w1t's size
  float*          Y       = (float*)w1t;

  if (o > ws_size) {   // workspace insufficient: fail visibly (zeros)
    hipMemsetAsync(d_out, 0, (size_t)out_size * 4, stream);
    return;
  }

  hipMemsetAsync(counts, 0, NEXP * 4, stream);

  prep_kernel<<<RTRB + TR1B + TR2B, 256, 0, stream>>>(
      x, rw, rb, topi, topw, counts, xb, w1, w1t, w2, w2t);
  permbuild_kernel<<<1, 256, 0, stream>>>(topi, counts, offsets, perm, islot);
  gemm128<DDIM, FDIM, true ><<<NEXP*MT128*(FDIM/128), 256, 0, stream>>>(xb, w1t, b1, perm, offsets, (void*)H);
  gemm128<FDIM, DDIM, false><<<NEXP*MT128*(DDIM/128), 256, 0, stream>>>(H, w2t, nullptr, nullptr, offsets, (void*)Y);
  combine_kernel<<<TTOK, 256, 0, stream>>>(Y, b2, topi, topw, islot, out);
}

// Round 14
// 737.347 us; speedup vs baseline: 1.4307x; 1.0037x over previous
//
#include <hip/hip_runtime.h>
#include <stdint.h>
#include <math.h>

#define TTOK 8192
#define DDIM 1024
#define FDIM 4096
#define NEXP 8
#define NASG (TTOK*2)
#define MT128 64   // max 128-row tiles per expert

#define RTRB (TTOK/4)                              // 2048 router blocks
#define TR1B (NEXP*(DDIM/64)*(FDIM/64))            // 8192 w1 tiles
#define TR2B (NEXP*(FDIM/64)*(DDIM/64))            // 8192 w2 tiles

typedef __attribute__((ext_vector_type(8))) short bf16x8;
typedef __attribute__((ext_vector_type(4))) float f32x4;
typedef __attribute__((ext_vector_type(4))) float f4v;
typedef __attribute__((ext_vector_type(4))) unsigned short u16x4;

__device__ __forceinline__ unsigned short f2bf(float f) {
  union { float f; unsigned int u; } v; v.f = f;
  unsigned int u = v.u;
  u += 0x7fffu + ((u >> 16) & 1u);   // round-to-nearest-even
  return (unsigned short)(u >> 16);
}

__device__ __forceinline__ void gload16(const void* g, void* l) {
  __builtin_amdgcn_global_load_lds(
    (__attribute__((address_space(1))) unsigned int*)(uintptr_t)g,
    (__attribute__((address_space(3))) unsigned int*)(uintptr_t)l,
    16, 0, 0);
}

// ===== prep: router (blocks 0..RTRB) + weight transpose (rest), co-scheduled =====
// router: one wave per token, fp64 accumulate, emits xb bf16 + topk + counts
// transpose: [E][R][C] f32 -> [E][C][R] bf16; float4 loads (16B/lane), ushort4 stores
__global__ __launch_bounds__(256) void prep_kernel(
    const float* __restrict__ x, const float* __restrict__ rw,
    const float* __restrict__ rb, int* __restrict__ topi,
    float* __restrict__ topw, int* __restrict__ counts,
    unsigned short* __restrict__ xb,
    const float* __restrict__ w1, unsigned short* __restrict__ w1t,
    const float* __restrict__ w2, unsigned short* __restrict__ w2t)
{
  __shared__ float tile[64][65];
  int blk = blockIdx.x;
  if (blk < RTRB) {
    int wave = threadIdx.x >> 6;
    int lane = threadIdx.x & 63;
    int t = blk * 4 + wave;
    if (t >= TTOK) return;
    double acc[8];
#pragma unroll
    for (int e = 0; e < 8; e++) acc[e] = 0.0;
    const float* xr = x + (size_t)t * DDIM;
    unsigned short* xbr = xb + (size_t)t * DDIM;
    for (int d = lane; d < DDIM; d += 64) {
      float xf = xr[d];
      xbr[d] = f2bf(xf);
      double xv = (double)xf;
      const float* rwr = rw + (size_t)d * 8;
#pragma unroll
      for (int e = 0; e < 8; e++) acc[e] += xv * (double)rwr[e];
    }
#pragma unroll
    for (int e = 0; e < 8; e++) {
      for (int off = 32; off >= 1; off >>= 1)
        acc[e] += __shfl_xor(acc[e], off);
    }
    if (lane == 0) {
      float lg[8];
#pragma unroll
      for (int e = 0; e < 8; e++) lg[e] = (float)acc[e] + rb[e];
      int i0 = 0;
      for (int e = 1; e < 8; e++) if (lg[e] > lg[i0]) i0 = e;   // ties -> lowest idx
      int i1 = -1;
      for (int e = 0; e < 8; e++) {
        if (e == i0) continue;
        if (i1 < 0 || lg[e] > lg[i1]) i1 = e;
      }
      double z = exp((double)lg[i1] - (double)lg[i0]);
      float w0 = (float)(1.0 / (1.0 + z));
      topi[t*2]   = i0;  topi[t*2+1] = i1;
      topw[t*2]   = w0;  topw[t*2+1] = 1.0f - w0;
      atomicAdd(&counts[i0], 1);
      atomicAdd(&counts[i1], 1);
    }
    return;
  }
  // ---- transpose part ----
  int b = blk - RTRB;
  const float* w; unsigned short* wt; int R, C;
  if (b < TR1B) { w = w1; wt = w1t; R = DDIM; C = FDIM; }
  else { b -= TR1B; w = w2; wt = w2t; R = FDIM; C = DDIM; }
  int tilesPerRow = C >> 6;
  int tilesPerMat = (R >> 6) * tilesPerRow;
  int e = b / tilesPerMat;
  int rem = b - e * tilesPerMat;
  int tr = rem / tilesPerRow;
  int tc = rem - tr * tilesPerRow;
  int tid = threadIdx.x;
  size_t ibase = (size_t)e*R*C + ((size_t)tr*64)*C + (size_t)tc*64;
  // phase 1: float4 loads (16B/lane), scalar LDS writes (2-way aliased, free)
#pragma unroll
  for (int i = 0; i < 4; i++) {
    int idx = tid + i*256;          // 0..1023
    int r  = idx >> 4;              // input row 0..63
    int c4 = (idx & 15) * 4;        // input col group
    f4v v = *(const f4v*)(w + ibase + (size_t)r*C + c4);
    tile[r][c4+0] = v[0];
    tile[r][c4+1] = v[1];
    tile[r][c4+2] = v[2];
    tile[r][c4+3] = v[3];
  }
  __syncthreads();
  // phase 2: output [C][R]: out[tc*64 + r][tr*64 + c] = tile[c][r]; 4 cols/lane
  size_t obase = (size_t)e*R*C + ((size_t)tc*64)*R + (size_t)tr*64;
#pragma unroll
  for (int i = 0; i < 4; i++) {
    int idx = tid + i*256;          // 0..1023
    int r  = idx >> 4;              // output row 0..63
    int c4 = (idx & 15) * 4;        // output col group
    u16x4 v;
    v[0] = f2bf(tile[c4+0][r]);
    v[1] = f2bf(tile[c4+1][r]);
    v[2] = f2bf(tile[c4+2][r]);
    v[3] = f2bf(tile[c4+3][r]);
    *(u16x4*)(wt + obase + (size_t)r*R + c4) = v;
  }
}

// ------ deterministic stable counting sort (single block; includes scan) ------
__global__ __launch_bounds__(256) void permbuild_kernel(
    const int* __restrict__ topi, const int* __restrict__ counts,
    int* __restrict__ offsets, int* __restrict__ perm, int* __restrict__ islot)
{
  __shared__ int hist[256 * 8];
  __shared__ int offs[NEXP + 1];
  int tid = threadIdx.x;
  if (tid == 0) {
    int s = 0;
    for (int e = 0; e < 8; e++) { offs[e] = s; s += counts[e]; }
    offs[8] = s;
    for (int e = 0; e <= 8; e++) offsets[e] = offs[e];
  }
  int cnt[8];
#pragma unroll
  for (int e = 0; e < 8; e++) cnt[e] = 0;
  int base = tid * 64;
  for (int i = 0; i < 64; i++) cnt[topi[base + i]]++;
#pragma unroll
  for (int e = 0; e < 8; e++) hist[tid*8 + e] = cnt[e];
  __syncthreads();
  if (tid < 8) {
    int s = 0;
    for (int th = 0; th < 256; th++) { int v = hist[th*8 + tid]; hist[th*8 + tid] = s; s += v; }
  }
  __syncthreads();
  int pos[8];
#pragma unroll
  for (int e = 0; e < 8; e++) pos[e] = offs[e] + hist[tid*8 + e];
  for (int i = 0; i < 64; i++) {
    int a = base + i;
    int e = topi[a];
    int p = pos[e]++;
    perm[p] = a >> 1;
    islot[a] = p;
  }
}

// ========= 128x128 grouped GEMM, m97-faithful (multi-block overlap) ==========
// r10-verbatim: 256 threads (4 waves, 2x2), per-wave 64x64. BK=64. LDS 32KB
// single buffer, 2 __syncthreads per K-step; ~3 blocks/CU hide the drains.
// NO __launch_bounds__ (r12 showed (256,5) -> VGPR 48, L2 thrash, 1.7x slower).
// Swizzle byte ^= (row&7)<<4: inverse on global src, fwd on ds reads.

template<int KDIM, int NDIM, bool GELU>
__global__ void gemm128(
    const unsigned short* __restrict__ Asrc,
    const unsigned short* __restrict__ Bsrc,
    const float* __restrict__ bias,
    const int* __restrict__ perm,
    const int* __restrict__ offsets,
    void* __restrict__ Cout)
{
  constexpr int KT = KDIM / 64;
  constexpr int NT = NDIM / 128;
  int b = blockIdx.x;
  int e = b / (MT128 * NT);
  int rem = b - e * (MT128 * NT);
  int rt = rem / NT;
  int nt = rem - rt * NT;
  int off = offsets[e];
  int n_e = offsets[e+1] - off;
  if (rt * 128 >= n_e) return;

  __shared__ __align__(16) unsigned short lds[2 * 128 * 64];   // 32 KiB
  char* ldsA = (char*)lds;            // A: 128 rows x 128B
  char* ldsB = (char*)lds + 16384;    // B: 128 rows x 128B

  int tid = threadIdx.x;
  int lane = tid & 63;
  int wid = tid >> 6;          // 0..3
  int wr = wid >> 1;           // 0..1 (M strip)
  int wc = wid & 1;            // 0..1 (N strip)
  int tb0 = (lane >> 4) * 16;
  int rA = wr*64 + (lane & 15);
  int rB = wc*64 + (lane & 15);
  int xa  = (rA & 7) << 4;
  int xbw = (rB & 7) << 4;
  int aks0 = rA*128 + ( tb0       ^ xa);
  int aks1 = rA*128 + ((64 + tb0) ^ xa);
  int bks0 = rB*128 + ( tb0       ^ xbw);
  int bks1 = rB*128 + ((64 + tb0) ^ xbw);

  // staging: 4 A-slots + 4 B-slots per thread (1024 slots = 128 rows x 8 chunks)
  const char* srcA[4];
  const char* srcB[4];
#pragma unroll
  for (int i = 0; i < 4; i++) {
    int slot = tid + i*256;
    int r = slot >> 3;
    int kc = (slot & 7) ^ (r & 7);   // inverse swizzle on global k-chunk
    int g = off + rt*128 + r;
    if (g > NASG-1) g = NASG-1;
    size_t ar = GELU ? (size_t)perm[g] : (size_t)g;
    srcA[i] = (const char*)Asrc + (ar * KDIM + (size_t)kc*8) * 2;
    int col = nt*128 + r;
    srcB[i] = (const char*)Bsrc + (((size_t)e*NDIM + col) * KDIM + (size_t)kc*8) * 2;
  }
  int dstOff = tid * 16;

  f32x4 acc[4][4];
#pragma unroll
  for (int m = 0; m < 4; m++)
#pragma unroll
    for (int n = 0; n < 4; n++) acc[m][n] = (f32x4){0.f,0.f,0.f,0.f};

#pragma unroll 1
  for (int kt = 0; kt < KT; ++kt) {
    __syncthreads();   // previous compute done before overwrite
#pragma unroll
    for (int i = 0; i < 4; i++) {
      gload16(srcA[i] + (size_t)kt*128, ldsA + dstOff + i*4096);
      gload16(srcB[i] + (size_t)kt*128, ldsB + dstOff + i*4096);
    }
    __syncthreads();   // compiler-inserted vmcnt(0) drain: tile ready
#pragma unroll
    for (int ks = 0; ks < 2; ks++) {
      int ao = ks ? aks1 : aks0;
      int bo = ks ? bks1 : bks0;
      bf16x8 a[4], bb[4];
#pragma unroll
      for (int mi = 0; mi < 4; mi++) a[mi]  = *(const bf16x8*)(ldsA + mi*2048 + ao);
#pragma unroll
      for (int ni = 0; ni < 4; ni++) bb[ni] = *(const bf16x8*)(ldsB + ni*2048 + bo);
#pragma unroll
      for (int mi = 0; mi < 4; mi++)
#pragma unroll
        for (int ni = 0; ni < 4; ni++)
          acc[mi][ni] = __builtin_amdgcn_mfma_f32_16x16x32_bf16(a[mi], bb[ni], acc[mi][ni], 0, 0, 0);
    }
  }

  // epilogue
  int rq = (lane >> 4) * 4;
  int lc = lane & 15;
  if (GELU) {
    unsigned short* H = (unsigned short*)Cout;
#pragma unroll
    for (int mi = 0; mi < 4; mi++)
#pragma unroll
      for (int j = 0; j < 4; j++) {
        int sl = rt*128 + wr*64 + mi*16 + rq + j;
        if (sl < n_e) {
          size_t hrow = (size_t)(off + sl) * NDIM;
#pragma unroll
          for (int ni = 0; ni < 4; ni++) {
            int col = nt*128 + wc*64 + ni*16 + lc;
            float v = acc[mi][ni][j] + bias[e*NDIM + col];
            float g = 0.5f * v * (1.0f + erff(v * 0.70710678118654752f));
            H[hrow + col] = f2bf(g);
          }
        }
      }
  } else {
    float* Y = (float*)Cout;
#pragma unroll
    for (int mi = 0; mi < 4; mi++)
#pragma unroll
      for (int j = 0; j < 4; j++) {
        int sl = rt*128 + wr*64 + mi*16 + rq + j;
        if (sl < n_e) {
          size_t yrow = (size_t)(off + sl) * NDIM;
#pragma unroll
          for (int ni = 0; ni < 4; ni++) {
            int col = nt*128 + wc*64 + ni*16 + lc;
            Y[yrow + col] = acc[mi][ni][j];
          }
        }
      }
  }
}

// ---------- combine: out[t] = sum_k w_k * (Y[slot_k] + b2[e_k]) ----------
__global__ __launch_bounds__(256) void combine_kernel(
    const float* __restrict__ Y, const float* __restrict__ b2,
    const int* __restrict__ topi, const float* __restrict__ topw,
    const int* __restrict__ islot, float* __restrict__ out)
{
  int t = blockIdx.x;
  int s0 = islot[t*2], s1 = islot[t*2+1];
  int e0 = topi[t*2],  e1 = topi[t*2+1];
  float w0 = topw[t*2], w1 = topw[t*2+1];
  int d = threadIdx.x * 4;
  f4v y0 = *(const f4v*)(Y + (size_t)s0*DDIM + d);
  f4v y1 = *(const f4v*)(Y + (size_t)s1*DDIM + d);
  f4v c0 = *(const f4v*)(b2 + (size_t)e0*DDIM + d);
  f4v c1 = *(const f4v*)(b2 + (size_t)e1*DDIM + d);
  f4v o = w0*(y0+c0) + w1*(y1+c1);
  *(f4v*)(out + (size_t)t*DDIM + d) = o;
}

extern "C" void kernel_launch(void* const* d_in, const int* in_sizes, int n_in,
                              void* d_out, int out_size, void* d_ws, size_t ws_size,
                              hipStream_t stream) {
  const float* x  = (const float*)d_in[0];
  const float* w1 = (const float*)d_in[1];
  const float* b1 = (const float*)d_in[2];
  const float* w2 = (const float*)d_in[3];
  const float* b2 = (const float*)d_in[4];
  const float* rw = (const float*)d_in[5];
  const float* rb = (const float*)d_in[6];
  float* out = (float*)d_out;

  char* p = (char*)d_ws;
  size_t o = 0;
  auto take = [&](size_t bytes) -> void* {
    void* r = p + o;
    o = (o + bytes + 255) & ~(size_t)255;
    return r;
  };
  int*            counts  = (int*)take(NEXP * 4);
  int*            offsets = (int*)take((NEXP + 1) * 4);
  int*            topi    = (int*)take((size_t)NASG * 4);
  float*          topw    = (float*)take((size_t)NASG * 4);
  int*            perm    = (int*)take((size_t)NASG * 4);
  int*            islot   = (int*)take((size_t)NASG * 4);
  unsigned short* w1t     = (unsigned short*)take((size_t)NEXP * FDIM * DDIM * 2);
  unsigned short* xb      = (unsigned short*)take((size_t)TTOK * DDIM * 2);
  unsigned short* w2t     = (unsigned short*)take((size_t)NEXP * DDIM * FDIM * 2);
  unsigned short* H       = (unsigned short*)take((size_t)NASG * FDIM * 2);
  // Y aliases w1t (dead after gemm1): NASG*DDIM*4 = 64 MiB = exactly w1t's size
  float*          Y       = (float*)w1t;

  if (o > ws_size) {   // workspace insufficient: fail visibly (zeros)
    hipMemsetAsync(d_out, 0, (size_t)out_size * 4, stream);
    return;
  }

  hipMemsetAsync(counts, 0, NEXP * 4, stream);

  prep_kernel<<<RTRB + TR1B + TR2B, 256, 0, stream>>>(
      x, rw, rb, topi, topw, counts, xb, w1, w1t, w2, w2t);
  permbuild_kernel<<<1, 256, 0, stream>>>(topi, counts, offsets, perm, islot);
  gemm128<DDIM, FDIM, true ><<<NEXP*MT128*(FDIM/128), 256, 0, stream>>>(xb, w1t, b1, perm, offsets, (void*)H);
  gemm128<FDIM, DDIM, false><<<NEXP*MT128*(DDIM/128), 256, 0, stream>>>(H, w2t, nullptr, nullptr, offsets, (void*)Y);
  combine_kernel<<<TTOK, 256, 0, stream>>>(Y, b2, topi, topw, islot, out);
}